// Round 15
// baseline (122.522 us; speedup 1.0000x reference)
//
#include <hip/hip_runtime.h>

typedef __bf16 bf16x8 __attribute__((ext_vector_type(8)));
typedef float f32x4 __attribute__((ext_vector_type(4)));
typedef unsigned int u32x4 __attribute__((ext_vector_type(4)));

__device__ __forceinline__ unsigned short f2bf(float f) {
  unsigned u = __builtin_bit_cast(unsigned, f);
  u += 0x7FFFu + ((u >> 16) & 1u);
  return (unsigned short)(u >> 16);
}

// async global->LDS, 16B/lane; LDS dest = wave-uniform base + lane*16 (HW rule)
__device__ __forceinline__ void gl2lds16(const void* g, void* l) {
  __builtin_amdgcn_global_load_lds((const __attribute__((address_space(1))) void*)g,
                                   (__attribute__((address_space(3))) void*)l, 16, 0, 0);
}

__device__ __forceinline__ bf16x8 cvt8v(f32x4 a, f32x4 b) {
  bf16x8 r;
  r[0] = (__bf16)a[0]; r[1] = (__bf16)a[1]; r[2] = (__bf16)a[2]; r[3] = (__bf16)a[3];
  r[4] = (__bf16)b[0]; r[5] = (__bf16)b[1]; r[6] = (__bf16)b[2]; r[7] = (__bf16)b[3];
  return r;
}

// ---------------- W transpose: W[512 f][512 d] f32 -> Wt[512 d][512 f] bf16 --------
__global__ void transpose_cvt(const float* __restrict__ in, unsigned short* __restrict__ out) {
  __shared__ float tile[32][33];
  const int r0 = blockIdx.x * 32, c0 = blockIdx.y * 32;
  const int tx = threadIdx.x, ty = threadIdx.y;
#pragma unroll
  for (int i = 0; i < 4; ++i) tile[ty + i * 8][tx] = in[(size_t)(r0 + ty + i * 8) * 512 + c0 + tx];
  __syncthreads();
#pragma unroll
  for (int i = 0; i < 4; ++i) {
    const int cc = ty + i * 8;
    out[(size_t)(c0 + cc) * 512 + r0 + tx] = f2bf(tile[tx][cc]);
  }
}

// ---------------- gemm_y (round-8 proven, unchanged): yT = (x@W)^T + mask ----------
__global__ __launch_bounds__(512, 1) void gemm_y(const float* __restrict__ A0,
                                                 const unsigned short* __restrict__ B0,
                                                 unsigned short* __restrict__ yT,
                                                 int* __restrict__ mask) {
  constexpr int APITCH = 512, BPITCH = 512, NT = 16;
  __shared__ __align__(16) char lds[131072];
  const int bid = blockIdx.x;
  const int mt = bid >> 1, nt = bid & 1;
  const int b = mt >> 4, m0 = (mt & 15) * 128, n0 = nt * 256;
  const float* Ab = A0 + ((size_t)b * 2048 + m0) * APITCH;
  const unsigned short* Bb = B0 + (size_t)n0 * BPITCH;

  const int tid = threadIdx.x, w = tid >> 6, L = tid & 63;
  const int wr = w >> 2, wc = w & 3, r = L & 15, hi = L >> 4;

  const char* aSrc = (const char*)(Ab + (size_t)(w * 16 + r) * APITCH + hi * 4);
  const char* bSrc0 = (const char*)(Bb + (size_t)(w * 32 + r) * BPITCH + hi * 8);
  const char* bSrc1 = (const char*)(Bb + (size_t)(w * 32 + 16 + r) * BPITCH + hi * 8);

  int aro[4], bro[4];
#pragma unroll
  for (int mi = 0; mi < 4; ++mi)
    aro[mi] = (((wr * 4 + mi) * 2 + (hi >> 1)) << 10) + ((hi & 1) << 9) + r * 16;
#pragma unroll
  for (int ni = 0; ni < 4; ++ni) bro[ni] = 16384 + ((wc * 4 + ni) << 10) + L * 16;

  f32x4 acc[4][4] = {};
  unsigned anz[4] = {0u, 0u, 0u, 0u};

#define STAGE(SLOT, TA)                                                          \
  {                                                                              \
    char* ls = lds + (SLOT) * 32768;                                             \
    gl2lds16(aSrc + (size_t)(TA) * 128, ls + ((w * 2 + 0) << 10));               \
    gl2lds16(aSrc + (size_t)(TA) * 128 + 64, ls + ((w * 2 + 1) << 10));          \
    gl2lds16(bSrc0 + (size_t)(TA) * 64, ls + 16384 + ((w * 2 + 0) << 10));       \
    gl2lds16(bSrc1 + (size_t)(TA) * 64, ls + 16384 + ((w * 2 + 1) << 10));       \
  }

  STAGE(0, 0)
  STAGE(1, 1)
  STAGE(2, 2)
  asm volatile("s_waitcnt vmcnt(8)" ::: "memory");
  __builtin_amdgcn_sched_barrier(0);
  __builtin_amdgcn_s_barrier();
  __builtin_amdgcn_sched_barrier(0);

#pragma unroll 1
  for (int t = 0; t < NT; ++t) {
    const int slot = (t + 3) & 3, cur = t & 3;
    const int ta = (t + 3 < NT) ? (t + 3) : (NT - 1);
    STAGE(slot, ta)
    __builtin_amdgcn_sched_barrier(0);
    const char* cb = lds + cur * 32768;

    bf16x8 bfr[4];
#pragma unroll
    for (int ni = 0; ni < 4; ++ni) bfr[ni] = *(const bf16x8*)(cb + bro[ni]);
    f32x4 lo0 = *(const f32x4*)(cb + aro[0]), hh0 = *(const f32x4*)(cb + aro[0] + 256);
    f32x4 lo1 = *(const f32x4*)(cb + aro[1]), hh1 = *(const f32x4*)(cb + aro[1] + 256);
    asm volatile("s_waitcnt lgkmcnt(0)" ::: "memory");
    __builtin_amdgcn_sched_barrier(0);
    if (wc == 0) {
      u32x4 u0 = __builtin_bit_cast(u32x4, lo0), u1 = __builtin_bit_cast(u32x4, hh0);
      anz[0] |= (u0[0] | u0[1] | u0[2] | u0[3] | u1[0] | u1[1] | u1[2] | u1[3]) & 0x7fffffffu;
      u32x4 v0 = __builtin_bit_cast(u32x4, lo1), v1 = __builtin_bit_cast(u32x4, hh1);
      anz[1] |= (v0[0] | v0[1] | v0[2] | v0[3] | v1[0] | v1[1] | v1[2] | v1[3]) & 0x7fffffffu;
    }
    bf16x8 af0 = cvt8v(lo0, hh0), af1 = cvt8v(lo1, hh1);
    __builtin_amdgcn_s_setprio(1);
#pragma unroll
    for (int ni = 0; ni < 4; ++ni)
      acc[0][ni] = __builtin_amdgcn_mfma_f32_16x16x32_bf16(af0, bfr[ni], acc[0][ni], 0, 0, 0);
#pragma unroll
    for (int ni = 0; ni < 4; ++ni)
      acc[1][ni] = __builtin_amdgcn_mfma_f32_16x16x32_bf16(af1, bfr[ni], acc[1][ni], 0, 0, 0);
    __builtin_amdgcn_s_setprio(0);

    f32x4 lo2 = *(const f32x4*)(cb + aro[2]), hh2 = *(const f32x4*)(cb + aro[2] + 256);
    f32x4 lo3 = *(const f32x4*)(cb + aro[3]), hh3 = *(const f32x4*)(cb + aro[3] + 256);
    asm volatile("s_waitcnt lgkmcnt(0)" ::: "memory");
    __builtin_amdgcn_sched_barrier(0);
    if (wc == 0) {
      u32x4 u0 = __builtin_bit_cast(u32x4, lo2), u1 = __builtin_bit_cast(u32x4, hh2);
      anz[2] |= (u0[0] | u0[1] | u0[2] | u0[3] | u1[0] | u1[1] | u1[2] | u1[3]) & 0x7fffffffu;
      u32x4 v0 = __builtin_bit_cast(u32x4, lo3), v1 = __builtin_bit_cast(u32x4, hh3);
      anz[3] |= (v0[0] | v0[1] | v0[2] | v0[3] | v1[0] | v1[1] | v1[2] | v1[3]) & 0x7fffffffu;
    }
    bf16x8 af2 = cvt8v(lo2, hh2), af3 = cvt8v(lo3, hh3);
    __builtin_amdgcn_s_setprio(1);
#pragma unroll
    for (int ni = 0; ni < 4; ++ni)
      acc[2][ni] = __builtin_amdgcn_mfma_f32_16x16x32_bf16(af2, bfr[ni], acc[2][ni], 0, 0, 0);
#pragma unroll
    for (int ni = 0; ni < 4; ++ni)
      acc[3][ni] = __builtin_amdgcn_mfma_f32_16x16x32_bf16(af3, bfr[ni], acc[3][ni], 0, 0, 0);
    __builtin_amdgcn_s_setprio(0);

    asm volatile("s_waitcnt vmcnt(8)" ::: "memory");
    __builtin_amdgcn_sched_barrier(0);
    __builtin_amdgcn_s_barrier();
    __builtin_amdgcn_sched_barrier(0);
  }
  asm volatile("s_waitcnt vmcnt(0)" ::: "memory");
#undef STAGE

  if (wc == 0) {
#pragma unroll
    for (int mi = 0; mi < 4; ++mi) {
      unsigned v = anz[mi];
      v |= __shfl_xor(v, 16);
      v |= __shfl_xor(v, 32);
      if (hi == 0) mask[b * 2048 + m0 + wr * 64 + mi * 16 + r] = (v != 0u) ? 1 : 0;
    }
  }
#pragma unroll
  for (int mi = 0; mi < 4; ++mi)
#pragma unroll
    for (int ni = 0; ni < 4; ++ni) {
      const int col = n0 + wc * 64 + ni * 16 + r;
      const int nrow = m0 + wr * 64 + mi * 16 + hi * 4;
      ushort4 s;
      s.x = f2bf(acc[mi][ni][0]);
      s.y = f2bf(acc[mi][ni][1]);
      s.z = f2bf(acc[mi][ni][2]);
      s.w = f2bf(acc[mi][ni][3]);
      *(ushort4*)(yT + (((size_t)b * 512 + col) << 11) + nrow) = s;
    }
}

// ---------------- gemm_big: out = relu(a @ y) * mask -------------------------------
// Round-1/2 structure (the highest measured ingest rate, 7.1 TB/s) at the best
// geometry: BM=128 x BN=256, BK=64 -> 256 blocks, traffic 396 MB (A 2x = 268 MB L3,
// B 16x = 128 MB XCD-pinned L2) vs R2's 655 MB. Plain compiler-managed loads ONLY:
// B direct global->reg dbuf (no LDS), A fp32->reg->cvt->LDS dbuf (XOR-swizzled,
// 0-conflict), one __syncthreads per K-step. No asm loads, no glds, no hand vmcnt.
template <int NT>
__global__ __launch_bounds__(512, 1) void gemm_bigr(const float* __restrict__ a,
                                                    const unsigned short* __restrict__ yT,
                                                    const int* __restrict__ mask,
                                                    float* __restrict__ out) {
  __shared__ __align__(16) char Abuf[2][16384];  // 128 rows x 64 k x bf16

  const int bid = blockIdx.x;
  const int b = bid & 7, idx = bid >> 3;         // batch -> XCD pin for yT[b]
  const int m0 = (idx & 15) * 128, n0 = (idx >> 4) * 256;
  const float* Ab = a + ((size_t)b * 2048 + m0) * 2048;
  const unsigned short* Bb = yT + ((size_t)b * 512 + n0) * 2048;

  const int tid = threadIdx.x, w = tid >> 6, L = tid & 63;
  const int wr = w >> 2, wc = w & 3, r = L & 15, hi = L >> 4;

  // A staging: thread -> row arow = tid>>2 (128 rows, 4 thr/row), 16 consecutive fp32
  const int arow = tid >> 2, ac4 = tid & 3;
  const float* ap = Ab + (size_t)arow * 2048 + ac4 * 16;
  // LDS write offsets for the two 16B bf16 chunks (chunk index p = ac4*2 + h)
  const int aw0 = arow * 128 + (((ac4 * 2 + 0) ^ (arow & 7)) << 4);
  const int aw1 = arow * 128 + (((ac4 * 2 + 1) ^ (arow & 7)) << 4);

  // A fragment read offsets: row = wr*64 + mi*16 + r, k-octet kk*32 + hi*8
  int aoff[4][2];
#pragma unroll
  for (int mi = 0; mi < 4; ++mi)
#pragma unroll
    for (int kk = 0; kk < 2; ++kk)
      aoff[mi][kk] = ((wr * 64 + mi * 16 + r) * 128 + kk * 64 + hi * 16) ^ ((r & 7) << 4);

  // B fragment pointers: col = n0 + wc*64 + ni*16 + r (yT row), k-octet hi*8
  const unsigned short* bp[4];
#pragma unroll
  for (int ni = 0; ni < 4; ++ni)
    bp[ni] = Bb + (size_t)(wc * 64 + ni * 16 + r) * 2048 + hi * 8;

  f32x4 acc[4][4] = {};
  bf16x8 bc0[4][2], bc1[4][2];
  f32x4 q0, q1, q2, q3;

  // prologue: B(0) -> bc0; A(0) -> regs -> cvt -> LDS buf0
#pragma unroll
  for (int ni = 0; ni < 4; ++ni)
#pragma unroll
    for (int kk = 0; kk < 2; ++kk) bc0[ni][kk] = *(const bf16x8*)(bp[ni] + kk * 32);
  q0 = *(const f32x4*)(ap);
  q1 = *(const f32x4*)(ap + 4);
  q2 = *(const f32x4*)(ap + 8);
  q3 = *(const f32x4*)(ap + 12);
  *(bf16x8*)(&Abuf[0][aw0]) = cvt8v(q0, q1);
  *(bf16x8*)(&Abuf[0][aw1]) = cvt8v(q2, q3);
  __syncthreads();

#define BIG_BODY(TT, BUF, BCC, BCN)                                             \
  {                                                                             \
    const int tn = (TT) + 1;                                                    \
    const bool more = (tn < NT);                                                \
    if (more) {                                                                 \
      _Pragma("unroll") for (int ni = 0; ni < 4; ++ni)                          \
          _Pragma("unroll") for (int kk = 0; kk < 2; ++kk)                      \
              BCN[ni][kk] = *(const bf16x8*)(bp[ni] + tn * 64 + kk * 32);       \
      const float* apn = ap + tn * 64;                                          \
      q0 = *(const f32x4*)(apn);                                                \
      q1 = *(const f32x4*)(apn + 4);                                            \
      q2 = *(const f32x4*)(apn + 8);                                            \
      q3 = *(const f32x4*)(apn + 12);                                           \
    }                                                                           \
    bf16x8 af[4][2];                                                            \
    _Pragma("unroll") for (int mi = 0; mi < 4; ++mi)                            \
        _Pragma("unroll") for (int kk = 0; kk < 2; ++kk)                        \
            af[mi][kk] = *(const bf16x8*)(&Abuf[BUF][aoff[mi][kk]]);            \
    _Pragma("unroll") for (int kk = 0; kk < 2; ++kk)                            \
        _Pragma("unroll") for (int mi = 0; mi < 4; ++mi)                        \
            _Pragma("unroll") for (int ni = 0; ni < 4; ++ni)                    \
                acc[mi][ni] = __builtin_amdgcn_mfma_f32_16x16x32_bf16(          \
                    af[mi][kk], BCC[ni][kk], acc[mi][ni], 0, 0, 0);             \
    if (more) {                                                                 \
      *(bf16x8*)(&Abuf[(BUF) ^ 1][aw0]) = cvt8v(q0, q1);                        \
      *(bf16x8*)(&Abuf[(BUF) ^ 1][aw1]) = cvt8v(q2, q3);                        \
      __syncthreads();                                                          \
    }                                                                           \
  }

#pragma unroll 1
  for (int t = 0; t < NT; t += 2) {
    BIG_BODY(t, 0, bc0, bc1)
    BIG_BODY(t + 1, 1, bc1, bc0)
  }
#undef BIG_BODY

  // epilogue: relu + row mask + fp32 store (64B-coalesced per 16-lane group)
  const int* mrow = mask + b * 2048 + m0 + wr * 64;
#pragma unroll
  for (int mi = 0; mi < 4; ++mi) {
    const int4 mv = *(const int4*)(mrow + mi * 16 + hi * 4);
    const int mvv[4] = {mv.x, mv.y, mv.z, mv.w};
#pragma unroll
    for (int ni = 0; ni < 4; ++ni) {
      const int col = n0 + wc * 64 + ni * 16 + r;
      float* op = out + (size_t)(b * 2048 + m0 + wr * 64 + mi * 16 + hi * 4) * 512 + col;
#pragma unroll
      for (int rr = 0; rr < 4; ++rr) {
        float v = fmaxf(acc[mi][ni][rr], 0.0f);
        if (mvv[rr] == 0) v = 0.0f;
        op[(size_t)rr * 512] = v;
      }
    }
  }
}

// ---------------- launch ----------------------------------------------------------
extern "C" void kernel_launch(void* const* d_in, const int* in_sizes, int n_in,
                              void* d_out, int out_size, void* d_ws, size_t ws_size,
                              hipStream_t stream) {
  const float* x = (const float*)d_in[0];   // [8][2048][512]
  const float* a = (const float*)d_in[1];   // [8][2048][2048]
  const float* wk = (const float*)d_in[2];  // [512][512]
  float* out = (float*)d_out;               // [8][2048][512]

  char* ws = (char*)d_ws;
  unsigned short* wT = (unsigned short*)ws;                 // 512 KB
  unsigned short* yT = (unsigned short*)(ws + (1u << 19));  // 16 MB
  int* mask = (int*)(ws + (1u << 19) + (16u << 20));        // 64 KB

  transpose_cvt<<<dim3(16, 16), dim3(32, 8), 0, stream>>>(wk, wT);
  // y^T = (x @ W)^T (bf16) + exact row mask.  M_flat=16384, N=512, K=512.
  gemm_y<<<256, 512, 0, stream>>>(x, wT, yT, mask);
  // out = relu(a @ y) * mask.  Per batch M=2048 (BM=128), N=512 (BN=256), K=2048.
  gemm_bigr<32><<<256, 512, 0, stream>>>(a, yT, mask, out);
}

// Round 17
// 102.078 us; speedup vs baseline: 1.2003x; 1.2003x over previous
//
#include <hip/hip_runtime.h>

typedef __bf16 bf16x8 __attribute__((ext_vector_type(8)));
typedef float f32x4 __attribute__((ext_vector_type(4)));
typedef unsigned int u32x4 __attribute__((ext_vector_type(4)));

__device__ __forceinline__ unsigned short f2bf(float f) {
  unsigned u = __builtin_bit_cast(unsigned, f);
  u += 0x7FFFu + ((u >> 16) & 1u);
  return (unsigned short)(u >> 16);
}

// async global->LDS, 16B/lane; LDS dest = wave-uniform base + lane*16 (HW rule)
__device__ __forceinline__ void gl2lds16(const void* g, void* l) {
  __builtin_amdgcn_global_load_lds((const __attribute__((address_space(1))) void*)g,
                                   (__attribute__((address_space(3))) void*)l, 16, 0, 0);
}

__device__ __forceinline__ bf16x8 cvt8v(f32x4 a, f32x4 b) {
  bf16x8 r;
  r[0] = (__bf16)a[0]; r[1] = (__bf16)a[1]; r[2] = (__bf16)a[2]; r[3] = (__bf16)a[3];
  r[4] = (__bf16)b[0]; r[5] = (__bf16)b[1]; r[6] = (__bf16)b[2]; r[7] = (__bf16)b[3];
  return r;
}

// ---------------- W transpose: W[512 f][512 d] f32 -> Wt[512 d][512 f] bf16 --------
__global__ void transpose_cvt(const float* __restrict__ in, unsigned short* __restrict__ out) {
  __shared__ float tile[32][33];
  const int r0 = blockIdx.x * 32, c0 = blockIdx.y * 32;
  const int tx = threadIdx.x, ty = threadIdx.y;
#pragma unroll
  for (int i = 0; i < 4; ++i) tile[ty + i * 8][tx] = in[(size_t)(r0 + ty + i * 8) * 512 + c0 + tx];
  __syncthreads();
#pragma unroll
  for (int i = 0; i < 4; ++i) {
    const int cc = ty + i * 8;
    out[(size_t)(c0 + cc) * 512 + r0 + tx] = f2bf(tile[tx][cc]);
  }
}

// ---------------- gemm_y (round-8 proven, unchanged): yT = (x@W)^T + mask ----------
__global__ __launch_bounds__(512, 1) void gemm_y(const float* __restrict__ A0,
                                                 const unsigned short* __restrict__ B0,
                                                 unsigned short* __restrict__ yT,
                                                 int* __restrict__ mask) {
  constexpr int APITCH = 512, BPITCH = 512, NT = 16;
  __shared__ __align__(16) char lds[131072];
  const int bid = blockIdx.x;
  const int mt = bid >> 1, nt = bid & 1;
  const int b = mt >> 4, m0 = (mt & 15) * 128, n0 = nt * 256;
  const float* Ab = A0 + ((size_t)b * 2048 + m0) * APITCH;
  const unsigned short* Bb = B0 + (size_t)n0 * BPITCH;

  const int tid = threadIdx.x, w = tid >> 6, L = tid & 63;
  const int wr = w >> 2, wc = w & 3, r = L & 15, hi = L >> 4;

  const char* aSrc = (const char*)(Ab + (size_t)(w * 16 + r) * APITCH + hi * 4);
  const char* bSrc0 = (const char*)(Bb + (size_t)(w * 32 + r) * BPITCH + hi * 8);
  const char* bSrc1 = (const char*)(Bb + (size_t)(w * 32 + 16 + r) * BPITCH + hi * 8);

  int aro[4], bro[4];
#pragma unroll
  for (int mi = 0; mi < 4; ++mi)
    aro[mi] = (((wr * 4 + mi) * 2 + (hi >> 1)) << 10) + ((hi & 1) << 9) + r * 16;
#pragma unroll
  for (int ni = 0; ni < 4; ++ni) bro[ni] = 16384 + ((wc * 4 + ni) << 10) + L * 16;

  f32x4 acc[4][4] = {};
  unsigned anz[4] = {0u, 0u, 0u, 0u};

#define STAGE(SLOT, TA)                                                          \
  {                                                                              \
    char* ls = lds + (SLOT) * 32768;                                             \
    gl2lds16(aSrc + (size_t)(TA) * 128, ls + ((w * 2 + 0) << 10));               \
    gl2lds16(aSrc + (size_t)(TA) * 128 + 64, ls + ((w * 2 + 1) << 10));          \
    gl2lds16(bSrc0 + (size_t)(TA) * 64, ls + 16384 + ((w * 2 + 0) << 10));       \
    gl2lds16(bSrc1 + (size_t)(TA) * 64, ls + 16384 + ((w * 2 + 1) << 10));       \
  }

  STAGE(0, 0)
  STAGE(1, 1)
  STAGE(2, 2)
  asm volatile("s_waitcnt vmcnt(8)" ::: "memory");
  __builtin_amdgcn_sched_barrier(0);
  __builtin_amdgcn_s_barrier();
  __builtin_amdgcn_sched_barrier(0);

#pragma unroll 1
  for (int t = 0; t < NT; ++t) {
    const int slot = (t + 3) & 3, cur = t & 3;
    const int ta = (t + 3 < NT) ? (t + 3) : (NT - 1);
    STAGE(slot, ta)
    __builtin_amdgcn_sched_barrier(0);
    const char* cb = lds + cur * 32768;

    bf16x8 bfr[4];
#pragma unroll
    for (int ni = 0; ni < 4; ++ni) bfr[ni] = *(const bf16x8*)(cb + bro[ni]);
    f32x4 lo0 = *(const f32x4*)(cb + aro[0]), hh0 = *(const f32x4*)(cb + aro[0] + 256);
    f32x4 lo1 = *(const f32x4*)(cb + aro[1]), hh1 = *(const f32x4*)(cb + aro[1] + 256);
    asm volatile("s_waitcnt lgkmcnt(0)" ::: "memory");
    __builtin_amdgcn_sched_barrier(0);
    if (wc == 0) {
      u32x4 u0 = __builtin_bit_cast(u32x4, lo0), u1 = __builtin_bit_cast(u32x4, hh0);
      anz[0] |= (u0[0] | u0[1] | u0[2] | u0[3] | u1[0] | u1[1] | u1[2] | u1[3]) & 0x7fffffffu;
      u32x4 v0 = __builtin_bit_cast(u32x4, lo1), v1 = __builtin_bit_cast(u32x4, hh1);
      anz[1] |= (v0[0] | v0[1] | v0[2] | v0[3] | v1[0] | v1[1] | v1[2] | v1[3]) & 0x7fffffffu;
    }
    bf16x8 af0 = cvt8v(lo0, hh0), af1 = cvt8v(lo1, hh1);
    __builtin_amdgcn_s_setprio(1);
#pragma unroll
    for (int ni = 0; ni < 4; ++ni)
      acc[0][ni] = __builtin_amdgcn_mfma_f32_16x16x32_bf16(af0, bfr[ni], acc[0][ni], 0, 0, 0);
#pragma unroll
    for (int ni = 0; ni < 4; ++ni)
      acc[1][ni] = __builtin_amdgcn_mfma_f32_16x16x32_bf16(af1, bfr[ni], acc[1][ni], 0, 0, 0);
    __builtin_amdgcn_s_setprio(0);

    f32x4 lo2 = *(const f32x4*)(cb + aro[2]), hh2 = *(const f32x4*)(cb + aro[2] + 256);
    f32x4 lo3 = *(const f32x4*)(cb + aro[3]), hh3 = *(const f32x4*)(cb + aro[3] + 256);
    asm volatile("s_waitcnt lgkmcnt(0)" ::: "memory");
    __builtin_amdgcn_sched_barrier(0);
    if (wc == 0) {
      u32x4 u0 = __builtin_bit_cast(u32x4, lo2), u1 = __builtin_bit_cast(u32x4, hh2);
      anz[2] |= (u0[0] | u0[1] | u0[2] | u0[3] | u1[0] | u1[1] | u1[2] | u1[3]) & 0x7fffffffu;
      u32x4 v0 = __builtin_bit_cast(u32x4, lo3), v1 = __builtin_bit_cast(u32x4, hh3);
      anz[3] |= (v0[0] | v0[1] | v0[2] | v0[3] | v1[0] | v1[1] | v1[2] | v1[3]) & 0x7fffffffu;
    }
    bf16x8 af2 = cvt8v(lo2, hh2), af3 = cvt8v(lo3, hh3);
    __builtin_amdgcn_s_setprio(1);
#pragma unroll
    for (int ni = 0; ni < 4; ++ni)
      acc[2][ni] = __builtin_amdgcn_mfma_f32_16x16x32_bf16(af2, bfr[ni], acc[2][ni], 0, 0, 0);
#pragma unroll
    for (int ni = 0; ni < 4; ++ni)
      acc[3][ni] = __builtin_amdgcn_mfma_f32_16x16x32_bf16(af3, bfr[ni], acc[3][ni], 0, 0, 0);
    __builtin_amdgcn_s_setprio(0);

    asm volatile("s_waitcnt vmcnt(8)" ::: "memory");
    __builtin_amdgcn_sched_barrier(0);
    __builtin_amdgcn_s_barrier();
    __builtin_amdgcn_sched_barrier(0);
  }
  asm volatile("s_waitcnt vmcnt(0)" ::: "memory");
#undef STAGE

  if (wc == 0) {
#pragma unroll
    for (int mi = 0; mi < 4; ++mi) {
      unsigned v = anz[mi];
      v |= __shfl_xor(v, 16);
      v |= __shfl_xor(v, 32);
      if (hi == 0) mask[b * 2048 + m0 + wr * 64 + mi * 16 + r] = (v != 0u) ? 1 : 0;
    }
  }
#pragma unroll
  for (int mi = 0; mi < 4; ++mi)
#pragma unroll
    for (int ni = 0; ni < 4; ++ni) {
      const int col = n0 + wc * 64 + ni * 16 + r;
      const int nrow = m0 + wr * 64 + mi * 16 + hi * 4;
      ushort4 s;
      s.x = f2bf(acc[mi][ni][0]);
      s.y = f2bf(acc[mi][ni][1]);
      s.z = f2bf(acc[mi][ni][2]);
      s.w = f2bf(acc[mi][ni][3]);
      *(ushort4*)(yT + (((size_t)b * 512 + col) << 11) + nrow) = s;
    }
}

// ---------------- gemm_pc: producer/consumer out = relu(a @ y) * mask --------------
// BM=128 x BN=256, BK=32, NT=64. 8 waves: waves 0-3 CONSUMERS (wave tile 64x128,
// acc[4][8]), waves 4-7 PRODUCERS. Ring of 4 x 32KB slots (A fp32 16KB | B bf16
// 16KB, R8-verified frag layout). No block barrier in the loop. ROUND-16 BUG FIX:
// signal atomics must be SINGLE-LANE (a full-wave atomicAdd bumps by 64/lane-count,
// m20) -> guard with (L == 0). Ordering: producer vmcnt(0) is wave-level (covers
// all lanes' glds) BEFORE lane-0 signals rdy; consumer lgkmcnt(0) completes all
// slot reads BEFORE lane-0 releases done.
template <int NT>
__global__ __launch_bounds__(512, 1) void gemm_pc(const float* __restrict__ a,
                                                  const unsigned short* __restrict__ yT,
                                                  const int* __restrict__ mask,
                                                  float* __restrict__ out) {
  __shared__ __align__(16) char slots[4][32768];
  __shared__ int rdy[4];
  __shared__ int done[4];

  const int bid = blockIdx.x;
  const int b = bid & 7, idx = bid >> 3;  // batch -> XCD pin for yT[b]
  const int m0 = (idx & 15) * 128, n0 = (idx >> 4) * 256;
  const float* Ab = a + ((size_t)b * 2048 + m0) * 2048;
  const unsigned short* Bb = yT + ((size_t)b * 512 + n0) * 2048;

  const int tid = threadIdx.x, w = tid >> 6, L = tid & 63;
  const int r = L & 15, hi = L >> 4;

  if (tid < 4) { rdy[tid] = 0; done[tid] = 0; }
  __syncthreads();  // the ONLY block-wide barrier

  volatile int* vrdy = rdy;
  volatile int* vdone = done;

  if (w >= 4) {
    // ---------------- producer wave (p = w-4): 8 glds/tile ----------------
    const int p = w - 4;
    const char* aS[4];
    const char* bS[4];
#pragma unroll
    for (int j = 0; j < 4; ++j) {
      const int g = p * 4 + j;
      // A region g: rows (g>>1)*16 + r, k-floats (g&1)*16 + hi*4  (R8 layout)
      aS[j] = (const char*)Ab + ((size_t)((g >> 1) * 16 + r) * 2048) * 4 + hi * 16 + (g & 1) * 64;
      // B region g: yT rows g*16 + r, k-bf16 hi*8
      bS[j] = (const char*)Bb + ((size_t)(g * 16 + r) * 2048) * 2 + hi * 16;
    }
#pragma unroll 1
    for (int t = 0; t < NT; ++t) {
      const int s = t & 3;
      const int gt = (t >> 2) * 4;  // all 4 consumers done with tile t-4
      while (vdone[s] < gt) __builtin_amdgcn_s_sleep(1);
      asm volatile("" ::: "memory");
      __builtin_amdgcn_sched_barrier(0);
      char* sb = slots[s];
#pragma unroll
      for (int j = 0; j < 4; ++j) {
        const int g = p * 4 + j;
        gl2lds16(aS[j] + (size_t)t * 128, sb + (g << 10));
        gl2lds16(bS[j] + (size_t)t * 64, sb + 16384 + (g << 10));
      }
      asm volatile("s_waitcnt vmcnt(0)" ::: "memory");  // own 8 glds landed (wave-level)
      __builtin_amdgcn_sched_barrier(0);
      if (L == 0) atomicAdd(&rdy[s], 1);  // SINGLE-LANE signal (R16 fix)
    }
    return;  // producers exit; consumers own the epilogue
  }

  // ---------------- consumer wave: wave tile 64(M) x 128(N) ----------------
  const int wr = w >> 1, wc = w & 1;
  int aro[4], bro[8];
#pragma unroll
  for (int mi = 0; mi < 4; ++mi)
    aro[mi] = (((wr * 4 + mi) * 2 + (hi >> 1)) << 10) + ((hi & 1) << 9) + r * 16;
#pragma unroll
  for (int ni = 0; ni < 8; ++ni) bro[ni] = 16384 + ((wc * 8 + ni) << 10) + L * 16;

  f32x4 acc[4][8] = {};

#pragma unroll 1
  for (int t = 0; t < NT; ++t) {
    const int s = t & 3;
    const int target = ((t >> 2) + 1) * 4;  // all 4 producers staged this gen
    while (vrdy[s] < target) __builtin_amdgcn_s_sleep(1);
    asm volatile("" ::: "memory");
    __builtin_amdgcn_sched_barrier(0);
    const char* sb = slots[s];

    bf16x8 bfr[8];
#pragma unroll
    for (int ni = 0; ni < 8; ++ni) bfr[ni] = *(const bf16x8*)(sb + bro[ni]);
    f32x4 lo[4], hh[4];
#pragma unroll
    for (int mi = 0; mi < 4; ++mi) {
      lo[mi] = *(const f32x4*)(sb + aro[mi]);
      hh[mi] = *(const f32x4*)(sb + aro[mi] + 256);
    }
    asm volatile("s_waitcnt lgkmcnt(0)" ::: "memory");  // slot reads complete
    __builtin_amdgcn_sched_barrier(0);
    if (L == 0) atomicAdd(&done[s], 1);  // SINGLE-LANE release (R16 fix)
    bf16x8 af[4];
#pragma unroll
    for (int mi = 0; mi < 4; ++mi) af[mi] = cvt8v(lo[mi], hh[mi]);
    __builtin_amdgcn_s_setprio(1);
#pragma unroll
    for (int mi = 0; mi < 4; ++mi)
#pragma unroll
      for (int ni = 0; ni < 8; ++ni)
        acc[mi][ni] = __builtin_amdgcn_mfma_f32_16x16x32_bf16(af[mi], bfr[ni], acc[mi][ni], 0, 0, 0);
    __builtin_amdgcn_s_setprio(0);
  }

  // epilogue: relu + row mask + fp32 store
  const int* mrow = mask + b * 2048 + m0 + wr * 64;
#pragma unroll
  for (int mi = 0; mi < 4; ++mi) {
    const int4 mv = *(const int4*)(mrow + mi * 16 + hi * 4);
    const int mvv[4] = {mv.x, mv.y, mv.z, mv.w};
#pragma unroll
    for (int ni = 0; ni < 8; ++ni) {
      const int col = n0 + wc * 128 + ni * 16 + r;
      float* op = out + (size_t)(b * 2048 + m0 + wr * 64 + mi * 16 + hi * 4) * 512 + col;
#pragma unroll
      for (int rr = 0; rr < 4; ++rr) {
        float v = fmaxf(acc[mi][ni][rr], 0.0f);
        if (mvv[rr] == 0) v = 0.0f;
        op[(size_t)rr * 512] = v;
      }
    }
  }
}

// ---------------- launch ----------------------------------------------------------
extern "C" void kernel_launch(void* const* d_in, const int* in_sizes, int n_in,
                              void* d_out, int out_size, void* d_ws, size_t ws_size,
                              hipStream_t stream) {
  const float* x = (const float*)d_in[0];   // [8][2048][512]
  const float* a = (const float*)d_in[1];   // [8][2048][2048]
  const float* wk = (const float*)d_in[2];  // [512][512]
  float* out = (float*)d_out;               // [8][2048][512]

  char* ws = (char*)d_ws;
  unsigned short* wT = (unsigned short*)ws;                 // 512 KB
  unsigned short* yT = (unsigned short*)(ws + (1u << 19));  // 16 MB
  int* mask = (int*)(ws + (1u << 19) + (16u << 20));        // 64 KB

  transpose_cvt<<<dim3(16, 16), dim3(32, 8), 0, stream>>>(wk, wT);
  // y^T = (x @ W)^T (bf16) + exact row mask.  M_flat=16384, N=512, K=512.
  gemm_y<<<256, 512, 0, stream>>>(x, wT, yT, mask);
  // out = relu(a @ y) * mask.  Per batch M=2048 (BM=128), N=512 (BN=256), K=2048.
  gemm_pc<64><<<256, 512, 0, stream>>>(a, yT, mask, out);
}